// Round 15
// baseline (69.432 us; speedup 1.0000x reference)
//
#include <hip/hip_runtime.h>

// Problem: N=65536 rows, H=512, E=8, OUT=2.
//   oh=x[:,0:8], delta=x[:,8], phi=x[:,9]
//   h  = relu(delta*w1 + b1 + phi*(oh@meta_w) + oh@meta_b)   -> one K=32 bf16 MFMA GEMM
//   h2 = relu(h @ w2 + b2)                                   -> main GEMM, bf16 MFMA, K=512
//   out = h2 @ w3 + b3                                       -> fused shuffle-reduce epilogue
//
// R15: async-DMA bf staging (T3/T4). Per-wave PRIVATE LDS ring (3 x 4KB/wave)
// filled by global_load_lds (no VGPR cost, no barriers -- wave-private data,
// per-wave vmcnt). 16 indep 16x16 accs. 1 block/CU (LDS 160KB exact) ->
// 2 waves/SIMD but 256-reg cap: the R3-R14 register war is moot. Counted
// vmcnt(8) = 2-slab lead; stage(t+3) issued after lgkmcnt(4) secures bf regs.

#define BM 64

typedef float f32x4 __attribute__((ext_vector_type(4)));
typedef short s16x8 __attribute__((ext_vector_type(8)));

__device__ __forceinline__ short f2bf(float f) {
    union { float f; unsigned u; } c; c.f = f;
    unsigned u = c.u;
    return (short)((u + 0x7FFFu + ((u >> 16) & 1u)) >> 16);  // RNE
}

__device__ __forceinline__ void gload16(const void* g, void* l) {
    __builtin_amdgcn_global_load_lds(
        (const __attribute__((address_space(1))) void*)g,
        (__attribute__((address_space(3))) void*)l, 16, 0, 0);
}

// ---------------- prep: build bf16 weight images in workspace ----------------
// w2s layout: [ks=16][g=4][n=512][j=8] bf16  (B-fragment order)
//   element (ks,g,n,j) = w2[k][n] with k = ks*32 + g*8 + j
// waugS layout: [col=512][k=32] bf16, rows of W' = [meta_w(8); meta_b(8); w1; b1; 0...]
__global__ void prep_kernel(const float* __restrict__ w1, const float* __restrict__ b1,
                            const float* __restrict__ mw, const float* __restrict__ mb,
                            const float* __restrict__ w2,
                            short* __restrict__ w2s, short* __restrict__ waugS) {
    int id = blockIdx.x * 256 + threadIdx.x;
    if (id < 512 * 512) {
        int k = id / 512, n = id % 512;
        int ks = k >> 5, g = (k >> 3) & 3, j = k & 7;
        w2s[(((ks * 4 + g) * 512) + n) * 8 + j] = f2bf(w2[id]);
    }
    if (id < 512 * 32) {
        int col = id >> 5, k = id & 31;
        float v = 0.f;
        if (k < 8)        v = mw[k * 512 + col];
        else if (k < 16)  v = mb[(k - 8) * 512 + col];
        else if (k == 16) v = w1[col];
        else if (k == 17) v = b1[col];
        waugS[col * 32 + k] = f2bf(v);
    }
}

// ---------------- fused MLP ----------------
// grid 1024 blocks x 512 threads (8 waves). Block tile: 64 rows x 512 cols.
// Wave w owns cols [w*64, w*64+64), all 64 rows -> acc 4(m) x 4(n) frags.
__global__ __launch_bounds__(512) void fused_mlp(
    const float* __restrict__ x, const short* __restrict__ waugS,
    const short* __restrict__ w2s, const float* __restrict__ b2,
    const float* __restrict__ w3, const float* __restrict__ b3,
    float* __restrict__ out) {

    // LDS map (163840 B exact):
    //   [0, 64K)        haug: h in fragment order, short idx = (k>>3)*512+row*8+(k&7)
    //   [64K, 160K)     bf rings: wave w slot s at 65536 + w*12288 + s*4096
    //   xls (2560B) + oacc (512B) overlay wave0-slot2 (dead until stage(2)/epilogue)
    __shared__ __align__(16) char Lall[163840];
    short* haug = (short*)Lall;
    char*  ring = Lall + 65536;

    const int tid  = threadIdx.x;
    const int wv   = tid >> 6;           // 0..7
    const int lane = tid & 63;
    const int l15  = lane & 15;
    const int g    = lane >> 4;
    const long rowbase = (long)blockIdx.x * BM;

    float* xls  = (float*)(ring + 2 * 4096);           // wave0 slot2
    float* oacc = (float*)(ring + 2 * 4096 + 2560);

    char* ringw = ring + wv * 12288;
    // per-lane global src base of this wave's bf stream (frag n at +n*256, slab t at +t*32768)
    const char* srcp = (const char*)w2s + g * 8192 + wv * 1024 + l15 * 16;

#define STAGE4(T, S)                                         \
    do {                                                     \
        const char* s_ = srcp + (size_t)(T) * 32768;         \
        char* d_ = ringw + (S) * 4096;                       \
        gload16(s_,       d_);                               \
        gload16(s_ + 256, d_ + 1024);                        \
        gload16(s_ + 512, d_ + 2048);                        \
        gload16(s_ + 768, d_ + 3072);                        \
    } while (0)

    // stage slabs 0,1 immediately (land during x-load + layer-1)
    STAGE4(0, 0);
    STAGE4(1, 1);

    // ---- load x tile (64x10 f32 = 640 floats) ----
    for (int i = tid; i < BM * 10; i += 512) xls[i] = x[rowbase * 10 + i];
    __syncthreads();

    // ---- layer 1: one K=32 MFMA pass; h -> LDS in fragment order ----
    {
        s16x8 afr[4];
#pragma unroll
        for (int m = 0; m < 4; ++m) {
            int r = m * 16 + l15;
            float v[8];
            if (g == 0) {                    // k=0..7 : oh * phi
                float phi = xls[r * 10 + 9];
#pragma unroll
                for (int j = 0; j < 8; ++j) v[j] = xls[r * 10 + j] * phi;
            } else if (g == 1) {             // k=8..15 : oh
#pragma unroll
                for (int j = 0; j < 8; ++j) v[j] = xls[r * 10 + j];
            } else if (g == 2) {             // k=16,17 : delta, 1
                v[0] = xls[r * 10 + 8]; v[1] = 1.f;
#pragma unroll
                for (int j = 2; j < 8; ++j) v[j] = 0.f;
            } else {                         // k=24..31 : 0
#pragma unroll
                for (int j = 0; j < 8; ++j) v[j] = 0.f;
            }
            s16x8 a;
#pragma unroll
            for (int j = 0; j < 8; ++j) a[j] = f2bf(v[j]);
            afr[m] = a;
        }
#pragma unroll
        for (int nf = 0; nf < 4; ++nf) {
            int col = wv * 64 + nf * 16 + l15;
            s16x8 bfr = *(const s16x8*)(waugS + col * 32 + g * 8);
            int chi = (col >> 3) * 512 + (col & 7);
#pragma unroll
            for (int m = 0; m < 4; ++m) {
                f32x4 c = {0.f, 0.f, 0.f, 0.f};
                c = __builtin_amdgcn_mfma_f32_16x16x32_bf16(afr[m], bfr, c, 0, 0, 0);
#pragma unroll
                for (int r4 = 0; r4 < 4; ++r4) {
                    int row = m * 16 + g * 4 + r4;
                    float hv = c[r4];
                    hv = hv > 0.f ? hv : 0.f;
                    haug[chi + row * 8] = f2bf(hv);
                }
            }
        }
    }
    __syncthreads();   // h ready; xls dead -> wave0 slot2 free; no more barriers in K-loop

    // stage slab 2 (wave0's overwrites xls region -- now dead)
    STAGE4(2, 2);

    // ---- layer 2: K=512, 16 fully-unrolled iters, per-wave ring, counted vmcnt ----
    f32x4 acc[4][4];
#pragma unroll
    for (int m = 0; m < 4; ++m)
#pragma unroll
        for (int n = 0; n < 4; ++n) acc[m][n] = (f32x4){0.f, 0.f, 0.f, 0.f};

    const char* hbp = (const char*)haug + g * 1024 + l15 * 16;   // af: +t*4096+m*256
    const char* rbl = ringw + (size_t)lane * 16;                 // bf: +S*4096+n*1024

#define WAITV8 do { asm volatile("s_waitcnt vmcnt(8)" ::: "memory"); __builtin_amdgcn_sched_barrier(0); } while (0)
#define WAITV4 do { asm volatile("s_waitcnt vmcnt(4)" ::: "memory"); __builtin_amdgcn_sched_barrier(0); } while (0)
#define WAITV0 do { asm volatile("s_waitcnt vmcnt(0)" ::: "memory"); __builtin_amdgcn_sched_barrier(0); } while (0)
#define LGKM4  do { asm volatile("s_waitcnt lgkmcnt(4)" ::: "memory"); __builtin_amdgcn_sched_barrier(0); } while (0)

#define ITER(T, S, DOSTAGE)                                                                  \
    do {                                                                                     \
        s16x8 b0 = *(const s16x8*)(rbl + (S) * 4096);                                        \
        s16x8 b1 = *(const s16x8*)(rbl + (S) * 4096 + 1024);                                 \
        s16x8 b2v = *(const s16x8*)(rbl + (S) * 4096 + 2048);                                \
        s16x8 b3v = *(const s16x8*)(rbl + (S) * 4096 + 3072);                                \
        __builtin_amdgcn_sched_barrier(0);                                                   \
        s16x8 a0 = *(const s16x8*)(hbp + (T) * 4096);                                        \
        s16x8 a1 = *(const s16x8*)(hbp + (T) * 4096 + 256);                                  \
        s16x8 a2 = *(const s16x8*)(hbp + (T) * 4096 + 512);                                  \
        s16x8 a3 = *(const s16x8*)(hbp + (T) * 4096 + 768);                                  \
        LGKM4;  /* bf regs secured (oldest 4 lgkm ops) before slot overwrite */              \
        if (DOSTAGE) STAGE4((T) + 3, S);                                                     \
        acc[0][0] = __builtin_amdgcn_mfma_f32_16x16x32_bf16(a0, b0,  acc[0][0], 0, 0, 0);    \
        acc[0][1] = __builtin_amdgcn_mfma_f32_16x16x32_bf16(a0, b1,  acc[0][1], 0, 0, 0);    \
        acc[0][2] = __builtin_amdgcn_mfma_f32_16x16x32_bf16(a0, b2v, acc[0][2], 0, 0, 0);    \
        acc[0][3] = __builtin_amdgcn_mfma_f32_16x16x32_bf16(a0, b3v, acc[0][3], 0, 0, 0);    \
        acc[1][0] = __builtin_amdgcn_mfma_f32_16x16x32_bf16(a1, b0,  acc[1][0], 0, 0, 0);    \
        acc[1][1] = __builtin_amdgcn_mfma_f32_16x16x32_bf16(a1, b1,  acc[1][1], 0, 0, 0);    \
        acc[1][2] = __builtin_amdgcn_mfma_f32_16x16x32_bf16(a1, b2v, acc[1][2], 0, 0, 0);    \
        acc[1][3] = __builtin_amdgcn_mfma_f32_16x16x32_bf16(a1, b3v, acc[1][3], 0, 0, 0);    \
        acc[2][0] = __builtin_amdgcn_mfma_f32_16x16x32_bf16(a2, b0,  acc[2][0], 0, 0, 0);    \
        acc[2][1] = __builtin_amdgcn_mfma_f32_16x16x32_bf16(a2, b1,  acc[2][1], 0, 0, 0);    \
        acc[2][2] = __builtin_amdgcn_mfma_f32_16x16x32_bf16(a2, b2v, acc[2][2], 0, 0, 0);    \
        acc[2][3] = __builtin_amdgcn_mfma_f32_16x16x32_bf16(a2, b3v, acc[2][3], 0, 0, 0);    \
        acc[3][0] = __builtin_amdgcn_mfma_f32_16x16x32_bf16(a3, b0,  acc[3][0], 0, 0, 0);    \
        acc[3][1] = __builtin_amdgcn_mfma_f32_16x16x32_bf16(a3, b1,  acc[3][1], 0, 0, 0);    \
        acc[3][2] = __builtin_amdgcn_mfma_f32_16x16x32_bf16(a3, b2v, acc[3][2], 0, 0, 0);    \
        acc[3][3] = __builtin_amdgcn_mfma_f32_16x16x32_bf16(a3, b3v, acc[3][3], 0, 0, 0);    \
    } while (0)

    WAITV8; ITER(0, 0, 1);
    WAITV8; ITER(1, 1, 1);
    WAITV8; ITER(2, 2, 1);
    WAITV8; ITER(3, 0, 1);
    WAITV8; ITER(4, 1, 1);
    WAITV8; ITER(5, 2, 1);
    WAITV8; ITER(6, 0, 1);
    WAITV8; ITER(7, 1, 1);
    WAITV8; ITER(8, 2, 1);
    WAITV8; ITER(9, 0, 1);
    WAITV8; ITER(10, 1, 1);
    WAITV8; ITER(11, 2, 1);
    WAITV8; ITER(12, 0, 1);     // stages slab 15 into slot 0
    WAITV8; ITER(13, 1, 0);
    WAITV4; ITER(14, 2, 0);
    WAITV0; ITER(15, 0, 0);

#undef ITER
#undef STAGE4

    // ---- layer 3: relu(acc+b2) @ w3, per-(m,r4) immediate reduce ----
    __syncthreads();                 // K-loop done everywhere; ring dead
    if (tid < 128) oacc[tid] = 0.f;  // oacc overlaid ring -> zero now
    __syncthreads();

    float bb2[4], w30[4], w31[4];
#pragma unroll
    for (int n = 0; n < 4; ++n) {
        int col = wv * 64 + n * 16 + l15;
        bb2[n] = b2[col];
        w30[n] = w3[col * 2 + 0];
        w31[n] = w3[col * 2 + 1];
    }
#pragma unroll
    for (int m = 0; m < 4; ++m) {
#pragma unroll
        for (int r4 = 0; r4 < 4; ++r4) {
            float s0 = 0.f, s1 = 0.f;
#pragma unroll
            for (int n = 0; n < 4; ++n) {
                float v = acc[m][n][r4] + bb2[n];
                v = v > 0.f ? v : 0.f;
                s0 += v * w30[n];
                s1 += v * w31[n];
            }
            s0 += __shfl_xor(s0, 1); s1 += __shfl_xor(s1, 1);
            s0 += __shfl_xor(s0, 2); s1 += __shfl_xor(s1, 2);
            s0 += __shfl_xor(s0, 4); s1 += __shfl_xor(s1, 4);
            s0 += __shfl_xor(s0, 8); s1 += __shfl_xor(s1, 8);
            if (l15 == 0) {
                int row = m * 16 + g * 4 + r4;
                atomicAdd(&oacc[row * 2 + 0], s0);
                atomicAdd(&oacc[row * 2 + 1], s1);
            }
        }
    }
    __syncthreads();

    if (tid < 128) {
        int row = tid >> 1, o = tid & 1;
        out[(rowbase + row) * 2 + o] = oacc[tid] + b3[o];
    }
}

extern "C" void kernel_launch(void* const* d_in, const int* in_sizes, int n_in,
                              void* d_out, int out_size, void* d_ws, size_t ws_size,
                              hipStream_t stream) {
    const float* x  = (const float*)d_in[0];
    const float* w1 = (const float*)d_in[1];
    const float* b1 = (const float*)d_in[2];
    const float* mw = (const float*)d_in[3];
    const float* mb = (const float*)d_in[4];
    const float* w2 = (const float*)d_in[5];
    const float* b2 = (const float*)d_in[6];
    const float* w3 = (const float*)d_in[7];
    const float* b3 = (const float*)d_in[8];
    float* out = (float*)d_out;

    short* w2s   = (short*)d_ws;          // 512 KB
    short* waugS = w2s + 512 * 512;       // 32 KB

    prep_kernel<<<1024, 256, 0, stream>>>(w1, b1, mw, mb, w2, w2s, waugS);
    fused_mlp<<<65536 / BM, 512, 0, stream>>>(x, waugS, w2s, b2, w3, b3, out);
}

// Round 16
// 59.371 us; speedup vs baseline: 1.1695x; 1.1695x over previous
//
#include <hip/hip_runtime.h>

// Problem: N=65536 rows, H=512, E=8, OUT=2.
//   oh=x[:,0:8], delta=x[:,8], phi=x[:,9]
//   h  = relu(delta*w1 + b1 + phi*(oh@meta_w) + oh@meta_b)   -> one K=32 bf16 MFMA GEMM
//   h2 = relu(h @ w2 + b2)                                   -> main GEMM, bf16 MFMA, K=512
//   out = h2 @ w3 + b3                                       -> fused shuffle-reduce epilogue
//
// R16: big wave tile + big register budget.
//   Wave tile 128 rows x 64 cols -> acc[8][4] = 128 AGPR, 32 INDEPENDENT
//   MFMAs/iter (620cy run, 2x R11). BM=128, 8 waves, 1 block/CU (haug 128KB),
//   __launch_bounds__(512,2) -> 256-reg cap: ping-pong bf prefetch + split-af
//   fit with slack (~200 regs peak). bf global->reg (no LDS round trip: R15
//   proved bf-via-LDS is LDS-BW-bound at 21 FLOP/LDS-byte; this shape is
//   52 B/cy/CU). L2 traffic 268MB (half of R11). Barrier-free K-loop.

#define BM 128

typedef float f32x4 __attribute__((ext_vector_type(4)));
typedef short s16x8 __attribute__((ext_vector_type(8)));

__device__ __forceinline__ short f2bf(float f) {
    union { float f; unsigned u; } c; c.f = f;
    unsigned u = c.u;
    return (short)((u + 0x7FFFu + ((u >> 16) & 1u)) >> 16);  // RNE
}

// ---------------- prep: build bf16 weight images in workspace ----------------
// w2s layout: [ks=16][g=4][n=512][j=8] bf16  (B-fragment order)
//   element (ks,g,n,j) = w2[k][n] with k = ks*32 + g*8 + j
// waugS layout: [col=512][k=32] bf16, rows of W' = [meta_w(8); meta_b(8); w1; b1; 0...]
__global__ void prep_kernel(const float* __restrict__ w1, const float* __restrict__ b1,
                            const float* __restrict__ mw, const float* __restrict__ mb,
                            const float* __restrict__ w2,
                            short* __restrict__ w2s, short* __restrict__ waugS) {
    int id = blockIdx.x * 256 + threadIdx.x;
    if (id < 512 * 512) {
        int k = id / 512, n = id % 512;
        int ks = k >> 5, g = (k >> 3) & 3, j = k & 7;
        w2s[(((ks * 4 + g) * 512) + n) * 8 + j] = f2bf(w2[id]);
    }
    if (id < 512 * 32) {
        int col = id >> 5, k = id & 31;
        float v = 0.f;
        if (k < 8)        v = mw[k * 512 + col];
        else if (k < 16)  v = mb[(k - 8) * 512 + col];
        else if (k == 16) v = w1[col];
        else if (k == 17) v = b1[col];
        waugS[col * 32 + k] = f2bf(v);
    }
}

// ---------------- fused MLP ----------------
// grid 512 blocks x 512 threads (8 waves). Block tile: 128 rows x 512 cols.
// Wave w owns cols [w*64, w*64+64), all 128 rows -> acc 8(m) x 4(n) frags.
__global__ __launch_bounds__(512, 2) void fused_mlp(
    const float* __restrict__ x, const short* __restrict__ waugS,
    const short* __restrict__ w2s, const float* __restrict__ b2,
    const float* __restrict__ w3, const float* __restrict__ b3,
    float* __restrict__ out) {

    // h in FRAGMENT order: short idx = (k>>3)*1024 + row*8 + (k&7)   (128 rows)
    __shared__ __align__(16) short haug[128 * 512];         // 128KB
    __shared__ float xls[128 * 10];                         // 5120 B
    __shared__ float oacc[256];                             // 1024 B

    const int tid  = threadIdx.x;
    const int wv   = tid >> 6;           // 0..7
    const int lane = tid & 63;
    const int l15  = lane & 15;
    const int g    = lane >> 4;
    const long rowbase = (long)blockIdx.x * BM;

    // ---- load x tile (128x10 f32 = 1280 floats), zero out-acc ----
    for (int i = tid; i < BM * 10; i += 512) xls[i] = x[rowbase * 10 + i];
    if (tid < 256) oacc[tid] = 0.f;
    __syncthreads();

    // ---- layer 1: one K=32 MFMA pass; h -> LDS in fragment order ----
    {
        s16x8 bfr[4];
#pragma unroll
        for (int nf = 0; nf < 4; ++nf) {
            int col = wv * 64 + nf * 16 + l15;
            bfr[nf] = *(const s16x8*)(waugS + col * 32 + g * 8);
        }
#pragma unroll
        for (int m = 0; m < 8; ++m) {
            int r = m * 16 + l15;
            float v[8];
            if (g == 0) {                    // k=0..7 : oh * phi
                float phi = xls[r * 10 + 9];
#pragma unroll
                for (int j = 0; j < 8; ++j) v[j] = xls[r * 10 + j] * phi;
            } else if (g == 1) {             // k=8..15 : oh
#pragma unroll
                for (int j = 0; j < 8; ++j) v[j] = xls[r * 10 + j];
            } else if (g == 2) {             // k=16,17 : delta, 1
                v[0] = xls[r * 10 + 8]; v[1] = 1.f;
#pragma unroll
                for (int j = 2; j < 8; ++j) v[j] = 0.f;
            } else {                         // k=24..31 : 0
#pragma unroll
                for (int j = 0; j < 8; ++j) v[j] = 0.f;
            }
            s16x8 a;
#pragma unroll
            for (int j = 0; j < 8; ++j) a[j] = f2bf(v[j]);
#pragma unroll
            for (int nf = 0; nf < 4; ++nf) {
                int col = wv * 64 + nf * 16 + l15;
                int chi = (col >> 3) * 1024 + (col & 7);
                f32x4 c = {0.f, 0.f, 0.f, 0.f};
                c = __builtin_amdgcn_mfma_f32_16x16x32_bf16(a, bfr[nf], c, 0, 0, 0);
#pragma unroll
                for (int r4 = 0; r4 < 4; ++r4) {
                    int row = m * 16 + g * 4 + r4;
                    float hv = c[r4];
                    hv = hv > 0.f ? hv : 0.f;
                    haug[chi + row * 8] = f2bf(hv);
                }
            }
        }
    }
    __syncthreads();   // h ready; haug read-only from here -> no more barriers

    // ---- layer 2: K=512 in 16 steps of 32; 32 indep MFMAs/iter,
    //      ping-pong bf prefetch (global->reg), split-af halves ----
    f32x4 acc[8][4];
#pragma unroll
    for (int m = 0; m < 8; ++m)
#pragma unroll
        for (int n = 0; n < 4; ++n) acc[m][n] = (f32x4){0.f, 0.f, 0.f, 0.f};

    // bf: byte = t*32768 + g*8192 + (wv*64+l15)*16 + n*256
    const char* bfp = (const char*)w2s + g * 8192 + (wv * 64 + l15) * 16;
    // af: byte = t*8192 + g*2048 + m*256 + l15*16
    const char* hbp = (const char*)haug + g * 2048 + l15 * 16;

#define LOADB(dst, T)                                                  \
    do {                                                               \
        dst[0] = *(const s16x8*)(bfp + (size_t)(T) * 32768);           \
        dst[1] = *(const s16x8*)(bfp + (size_t)(T) * 32768 + 256);     \
        dst[2] = *(const s16x8*)(bfp + (size_t)(T) * 32768 + 512);     \
        dst[3] = *(const s16x8*)(bfp + (size_t)(T) * 32768 + 768);     \
    } while (0)

#define HALF(bfv, MB)                                                                            \
    do {                                                                                         \
        s16x8 a0 = *(const s16x8*)(hbp + (MB) * 1024);                                           \
        s16x8 a1 = *(const s16x8*)(hbp + (MB) * 1024 + 256);                                     \
        s16x8 a2 = *(const s16x8*)(hbp + (MB) * 1024 + 512);                                     \
        s16x8 a3 = *(const s16x8*)(hbp + (MB) * 1024 + 768);                                     \
        acc[(MB)*4+0][0] = __builtin_amdgcn_mfma_f32_16x16x32_bf16(a0, bfv[0], acc[(MB)*4+0][0], 0, 0, 0); \
        acc[(MB)*4+0][1] = __builtin_amdgcn_mfma_f32_16x16x32_bf16(a0, bfv[1], acc[(MB)*4+0][1], 0, 0, 0); \
        acc[(MB)*4+0][2] = __builtin_amdgcn_mfma_f32_16x16x32_bf16(a0, bfv[2], acc[(MB)*4+0][2], 0, 0, 0); \
        acc[(MB)*4+0][3] = __builtin_amdgcn_mfma_f32_16x16x32_bf16(a0, bfv[3], acc[(MB)*4+0][3], 0, 0, 0); \
        acc[(MB)*4+1][0] = __builtin_amdgcn_mfma_f32_16x16x32_bf16(a1, bfv[0], acc[(MB)*4+1][0], 0, 0, 0); \
        acc[(MB)*4+1][1] = __builtin_amdgcn_mfma_f32_16x16x32_bf16(a1, bfv[1], acc[(MB)*4+1][1], 0, 0, 0); \
        acc[(MB)*4+1][2] = __builtin_amdgcn_mfma_f32_16x16x32_bf16(a1, bfv[2], acc[(MB)*4+1][2], 0, 0, 0); \
        acc[(MB)*4+1][3] = __builtin_amdgcn_mfma_f32_16x16x32_bf16(a1, bfv[3], acc[(MB)*4+1][3], 0, 0, 0); \
        acc[(MB)*4+2][0] = __builtin_amdgcn_mfma_f32_16x16x32_bf16(a2, bfv[0], acc[(MB)*4+2][0], 0, 0, 0); \
        acc[(MB)*4+2][1] = __builtin_amdgcn_mfma_f32_16x16x32_bf16(a2, bfv[1], acc[(MB)*4+2][1], 0, 0, 0); \
        acc[(MB)*4+2][2] = __builtin_amdgcn_mfma_f32_16x16x32_bf16(a2, bfv[2], acc[(MB)*4+2][2], 0, 0, 0); \
        acc[(MB)*4+2][3] = __builtin_amdgcn_mfma_f32_16x16x32_bf16(a2, bfv[3], acc[(MB)*4+2][3], 0, 0, 0); \
        acc[(MB)*4+3][0] = __builtin_amdgcn_mfma_f32_16x16x32_bf16(a3, bfv[0], acc[(MB)*4+3][0], 0, 0, 0); \
        acc[(MB)*4+3][1] = __builtin_amdgcn_mfma_f32_16x16x32_bf16(a3, bfv[1], acc[(MB)*4+3][1], 0, 0, 0); \
        acc[(MB)*4+3][2] = __builtin_amdgcn_mfma_f32_16x16x32_bf16(a3, bfv[2], acc[(MB)*4+3][2], 0, 0, 0); \
        acc[(MB)*4+3][3] = __builtin_amdgcn_mfma_f32_16x16x32_bf16(a3, bfv[3], acc[(MB)*4+3][3], 0, 0, 0); \
    } while (0)

#define DOSTEP(bfv) do { HALF(bfv, 0); HALF(bfv, 1); hbp += 8192; } while (0)

    s16x8 bfA[4], bfB[4];
    LOADB(bfA, 0);                            // t=0

#pragma unroll 1
    for (int tt = 0; tt < 7; ++tt) {
        LOADB(bfB, 2 * tt + 1);               // prefetch odd t
        DOSTEP(bfA);                          // consume t = 2tt
        LOADB(bfA, 2 * tt + 2);               // prefetch next even t
        DOSTEP(bfB);                          // consume t = 2tt+1
    }
    LOADB(bfB, 15);                           // last slice
    DOSTEP(bfA);                              // t=14
    DOSTEP(bfB);                              // t=15

#undef LOADB
#undef HALF
#undef DOSTEP

    // ---- layer 3: relu(acc+b2) @ w3, per-(m,r4) immediate reduce ----
    float bb2[4], w30[4], w31[4];
#pragma unroll
    for (int n = 0; n < 4; ++n) {
        int col = wv * 64 + n * 16 + l15;
        bb2[n] = b2[col];
        w30[n] = w3[col * 2 + 0];
        w31[n] = w3[col * 2 + 1];
    }
#pragma unroll
    for (int m = 0; m < 8; ++m) {
#pragma unroll
        for (int r4 = 0; r4 < 4; ++r4) {
            float s0 = 0.f, s1 = 0.f;
#pragma unroll
            for (int n = 0; n < 4; ++n) {
                float v = acc[m][n][r4] + bb2[n];
                v = v > 0.f ? v : 0.f;
                s0 += v * w30[n];
                s1 += v * w31[n];
            }
            s0 += __shfl_xor(s0, 1); s1 += __shfl_xor(s1, 1);
            s0 += __shfl_xor(s0, 2); s1 += __shfl_xor(s1, 2);
            s0 += __shfl_xor(s0, 4); s1 += __shfl_xor(s1, 4);
            s0 += __shfl_xor(s0, 8); s1 += __shfl_xor(s1, 8);
            if (l15 == 0) {
                int row = m * 16 + g * 4 + r4;
                atomicAdd(&oacc[row * 2 + 0], s0);
                atomicAdd(&oacc[row * 2 + 1], s1);
            }
        }
    }
    __syncthreads();

    if (tid < 256) {
        int row = tid >> 1, o = tid & 1;
        out[(rowbase + row) * 2 + o] = oacc[tid] + b3[o];
    }
}

extern "C" void kernel_launch(void* const* d_in, const int* in_sizes, int n_in,
                              void* d_out, int out_size, void* d_ws, size_t ws_size,
                              hipStream_t stream) {
    const float* x  = (const float*)d_in[0];
    const float* w1 = (const float*)d_in[1];
    const float* b1 = (const float*)d_in[2];
    const float* mw = (const float*)d_in[3];
    const float* mb = (const float*)d_in[4];
    const float* w2 = (const float*)d_in[5];
    const float* b2 = (const float*)d_in[6];
    const float* w3 = (const float*)d_in[7];
    const float* b3 = (const float*)d_in[8];
    float* out = (float*)d_out;

    short* w2s   = (short*)d_ws;          // 512 KB
    short* waugS = w2s + 512 * 512;       // 32 KB (also prefetch-overrun pad)

    prep_kernel<<<1024, 256, 0, stream>>>(w1, b1, mw, mb, w2, w2s, waugS);
    fused_mlp<<<65536 / BM, 512, 0, stream>>>(x, waugS, w2s, b2, w3, b3, out);
}